// Round 3
// baseline (866.487 us; speedup 1.0000x reference)
//
#include <hip/hip_runtime.h>

#define DIM   2048
#define NEXP  64
#define NTOK  32768
#define DC    64                 // d-chunk per stage
#define NC    (DIM / DC)         // 32 chunks
#define TB    64                 // tokens per block (one 64x64 tile, 4 waves k-split)
#define NBLK  (NTOK / TB)        // 512 blocks = exactly 2/CU
#define BUFF  8192               // floats per buffer: W[64][64] + xT[64][64]
#define XOFF  4096
#define DLDS  (2 * BUFF)         // denom scratch (floats)

typedef __attribute__((address_space(1))) const void gvoid_t;
typedef __attribute__((address_space(3))) void lvoid_t;
#define GLDS16(g, l) __builtin_amdgcn_global_load_lds((gvoid_t*)(g), (lvoid_t*)(l), 16, 0, 0)

__global__ void zero_denom_kernel(float* __restrict__ denom) {
    denom[threadIdx.x] = 0.0f;
}

__global__ __launch_bounds__(256, 2)
void gate_kernel(const float* __restrict__ x, const float* __restrict__ w,
                 const float* __restrict__ b, float* __restrict__ out,
                 float* __restrict__ denom)
{
    __shared__ float lds[2 * BUFF + NEXP];   // 65792 B -> 2 blocks/CU

    const int tid  = threadIdx.x;
    const int lane = tid & 63;
    const int wv   = tid >> 6;
    const int tg   = lane >> 3;     // token group (8 tokens each)
    const int eg   = lane & 7;      // expert group (8 experts each)
    const int tok0 = blockIdx.x * TB;

    if (tid < NEXP) lds[DLDS + tid] = 0.0f;

    // ---- x staging assignment: thread stages token xt, float4-column set xj
    const int tl = lane >> 2;            // 0..15
    const int xj = lane & 3;             // 0..3
    const int xt = wv * 16 + tl;         // block-local token
    const float* xrow = x + (size_t)(tok0 + xt) * DIM;

    // W chunk: contiguous 16KB, direct global->LDS DMA (linear dest)
    auto stageW = [&](int bsel, int c) {
        const float* wsrc = w + (size_t)c * (DC * NEXP);
        float* base = lds + bsel * BUFF;
#pragma unroll
        for (int i = 0; i < 4; ++i) {
            const int of = (wv * 4 + i) * 256 + lane * 4;   // linear in lane
            GLDS16(wsrc + of, base + of);
        }
    };
    // x chunk: coalesced float4 loads to regs (issue early), transpose via ds_write
    auto loadX = [&](float4* xf, int c) {
#pragma unroll
        for (int k = 0; k < 4; ++k)
            xf[k] = *(const float4*)(xrow + c * DC + (k * 4 + xj) * 4);
    };
    auto writeX = [&](const float4* xf, int bsel) {
        float* xb = lds + bsel * BUFF + XOFF;
#pragma unroll
        for (int k = 0; k < 4; ++k) {
            const int d0 = (k * 4 + xj) * 4;
#pragma unroll
            for (int i = 0; i < 4; ++i)
                xb[(d0 + i) * 64 + xt] = ((const float*)&xf[k])[i];  // xT[d][t]
        }
    };

    float acc[8][8];
#pragma unroll
    for (int i = 0; i < 8; ++i)
#pragma unroll
        for (int j = 0; j < 8; ++j) acc[i][j] = 0.0f;
    float ca[8][8];

    float4 xf[4];
    stageW(0, 0); loadX(xf, 0); writeX(xf, 0);
    __syncthreads();

    for (int c = 0; c < NC; ++c) {
        const int cur = c & 1;
        if (c + 1 < NC) { stageW(cur ^ 1, c + 1); loadX(xf, c + 1); }

        // compute wave's 16-d slice of chunk: 8x8 register tile, 4 LDS reads/d
        {
            const float* wb = lds + cur * BUFF;          // W[d][e]
            const float* xb = wb + XOFF;                 // xT[d][t]
#pragma unroll
            for (int dd = 0; dd < 16; ++dd) {
                const int dl = (wv * 16 + dd) * 64;
                const float4 xa = *(const float4*)(xb + dl + tg * 8);
                const float4 xc = *(const float4*)(xb + dl + tg * 8 + 4);
                const float4 wa = *(const float4*)(wb + dl + eg * 8);
                const float4 wc = *(const float4*)(wb + dl + eg * 8 + 4);
                const float xr[8] = {xa.x, xa.y, xa.z, xa.w, xc.x, xc.y, xc.z, xc.w};
                const float wr[8] = {wa.x, wa.y, wa.z, wa.w, wc.x, wc.y, wc.z, wc.w};
                if (dd == 0) {
#pragma unroll
                    for (int i = 0; i < 8; ++i)
#pragma unroll
                        for (int j = 0; j < 8; ++j) ca[i][j] = xr[i] * wr[j];
                } else {
#pragma unroll
                    for (int i = 0; i < 8; ++i)
#pragma unroll
                        for (int j = 0; j < 8; ++j) ca[i][j] = fmaf(xr[i], wr[j], ca[i][j]);
                }
            }
        }

        if (c + 1 < NC) writeX(xf, cur ^ 1);   // vmcnt-waits on xf, hidden by compute
        __syncthreads();

        // two-level fold (register-only, after barrier)
#pragma unroll
        for (int i = 0; i < 8; ++i)
#pragma unroll
            for (int j = 0; j < 8; ++j) acc[i][j] += ca[i][j];
    }

    // ---- cross-wave k-reduction via LDS tiles (buffers are dead now)
    {
        float* tw = lds + wv * 4096;     // tile[wv][t][e]
#pragma unroll
        for (int i = 0; i < 8; ++i) {
            float4 lo = {acc[i][0], acc[i][1], acc[i][2], acc[i][3]};
            float4 hi = {acc[i][4], acc[i][5], acc[i][6], acc[i][7]};
            *(float4*)(tw + (tg * 8 + i) * 64 + eg * 8)     = lo;
            *(float4*)(tw + (tg * 8 + i) * 64 + eg * 8 + 4) = hi;
        }
    }
    __syncthreads();

    // ---- epilogue: wave wv owns tokens [wv*16, wv*16+16), lane = expert
    const float bias = b[lane];
    for (int tt = 0; tt < 16; ++tt) {
        const int t = wv * 16 + tt;
        float v = bias;
        v += lds[0 * 4096 + t * 64 + lane];
        v += lds[1 * 4096 + t * 64 + lane];
        v += lds[2 * 4096 + t * 64 + lane];
        v += lds[3 * 4096 + t * 64 + lane];

        // wave argmax, FIRST index on ties (matches jnp.argmax)
        float m = v; int mi = lane;
#pragma unroll
        for (int off = 32; off > 0; off >>= 1) {
            float om = __shfl_xor(m, off);
            int   oi = __shfl_xor(mi, off);
            if (om > m || (om == m && oi < mi)) { m = om; mi = oi; }
        }
        float s = __expf(v - m);
#pragma unroll
        for (int off = 32; off > 0; off >>= 1) s += __shfl_xor(s, off);
        const float g = 1.0f / s;   // top-1 gate = exp(0)/sum

        out[(size_t)(tok0 + t) * NEXP + lane] = (lane == mi) ? g : 0.0f;
        if (lane == mi) atomicAdd(&lds[DLDS + lane], g);
    }

    __syncthreads();
    if (tid < NEXP) atomicAdd(&denom[tid], lds[DLDS + tid]);
}

// out[n,e] *= capacity / (denom[e] + eps); zeros stay zero (branch-free)
__global__ __launch_bounds__(256)
void scale_kernel(float* __restrict__ out, const float* __restrict__ denom)
{
    __shared__ float sc[NEXP];
    if (threadIdx.x < NEXP)
        sc[threadIdx.x] = (float)NTOK / (denom[threadIdx.x] + 1e-6f);
    __syncthreads();

    const size_t i = (size_t)blockIdx.x * blockDim.x + threadIdx.x; // float4 idx
    float4 v = ((const float4*)out)[i];
    const int e0 = (int)((i * 4) & (NEXP - 1));
    v.x *= sc[e0]; v.y *= sc[e0 + 1]; v.z *= sc[e0 + 2]; v.w *= sc[e0 + 3];
    ((float4*)out)[i] = v;
}

extern "C" void kernel_launch(void* const* d_in, const int* in_sizes, int n_in,
                              void* d_out, int out_size, void* d_ws, size_t ws_size,
                              hipStream_t stream) {
    const float* x = (const float*)d_in[0];
    const float* w = (const float*)d_in[1];
    const float* b = (const float*)d_in[2];
    float* out   = (float*)d_out;
    float* denom = (float*)d_ws;   // 64 floats

    zero_denom_kernel<<<1, NEXP, 0, stream>>>(denom);
    gate_kernel<<<NBLK, 256, 0, stream>>>(x, w, b, out, denom);
    scale_kernel<<<(NTOK * NEXP / 4) / 256, 256, 0, stream>>>(out, denom);
}

// Round 4
// 143.776 us; speedup vs baseline: 6.0267x; 6.0267x over previous
//
#include <hip/hip_runtime.h>

#define DIM   2048
#define NEXP  64
#define NTOK  32768
#define DC    64                 // d-chunk per stage
#define NC    (DIM / DC)         // 32 chunks
#define TB    64                 // tokens per block (one 64x64 tile, 4 waves k-split)
#define NBLK  (NTOK / TB)        // 512 blocks = exactly 2/CU
#define BUFF  8192               // floats per buffer: W[64][64] + xT[64][64]
#define XOFF  4096
#define DLDS  (2 * BUFF)         // denom scratch (floats)

typedef __attribute__((address_space(1))) const void gvoid_t;
typedef __attribute__((address_space(3))) void lvoid_t;
#define GLDS16(g, l) __builtin_amdgcn_global_load_lds((gvoid_t*)(g), (lvoid_t*)(l), 16, 0, 0)

__global__ void zero_denom_kernel(float* __restrict__ denom) {
    denom[threadIdx.x] = 0.0f;
}

// static-indexed FMA row: acc[i][0..7] += xs * {wa,wc}
#define FMA_ROW(i, xs)                         \
    acc[i][0] = fmaf((xs), wa.x, acc[i][0]);   \
    acc[i][1] = fmaf((xs), wa.y, acc[i][1]);   \
    acc[i][2] = fmaf((xs), wa.z, acc[i][2]);   \
    acc[i][3] = fmaf((xs), wa.w, acc[i][3]);   \
    acc[i][4] = fmaf((xs), wc.x, acc[i][4]);   \
    acc[i][5] = fmaf((xs), wc.y, acc[i][5]);   \
    acc[i][6] = fmaf((xs), wc.z, acc[i][6]);   \
    acc[i][7] = fmaf((xs), wc.w, acc[i][7]);

__global__ __launch_bounds__(256, 2)
void gate_kernel(const float* __restrict__ x, const float* __restrict__ w,
                 const float* __restrict__ b, float* __restrict__ out,
                 float* __restrict__ denom)
{
    __shared__ float lds[2 * BUFF + NEXP];   // 65792 B -> 2 blocks/CU

    const int tid  = threadIdx.x;
    const int lane = tid & 63;
    const int wv   = tid >> 6;
    const int tg   = lane >> 3;     // token group (8 tokens each)
    const int eg   = lane & 7;      // expert group (8 experts each)
    const int tok0 = blockIdx.x * TB;

    if (tid < NEXP) lds[DLDS + tid] = 0.0f;

    // ---- x staging assignment: thread stages token xt, float4-column set xj
    const int tl = lane >> 2;            // 0..15
    const int xj = lane & 3;             // 0..3
    const int xt = wv * 16 + tl;         // block-local token
    const float* xrow = x + (size_t)(tok0 + xt) * DIM;

    // W chunk: contiguous 16KB, direct global->LDS DMA (linear dest)
    auto stageW = [&](int bsel, int c) {
        const float* wsrc = w + (size_t)c * (DC * NEXP);
        float* base = lds + bsel * BUFF;
#pragma unroll
        for (int i = 0; i < 4; ++i) {
            const int of = (wv * 4 + i) * 256 + lane * 4;   // linear in lane
            GLDS16(wsrc + of, base + of);
        }
    };
    // x chunk: coalesced float4 loads to regs (issue early), transpose via ds_write
    auto loadX = [&](float4* xf, int c) {
#pragma unroll
        for (int k = 0; k < 4; ++k)
            xf[k] = *(const float4*)(xrow + c * DC + (k * 4 + xj) * 4);
    };
    auto writeX = [&](const float4* xf, int bsel) {
        float* xb = lds + bsel * BUFF + XOFF;
#pragma unroll
        for (int k = 0; k < 4; ++k) {
            const int d0 = (k * 4 + xj) * 4;
            xb[(d0 + 0) * 64 + xt] = xf[k].x;    // xT[d][t]
            xb[(d0 + 1) * 64 + xt] = xf[k].y;
            xb[(d0 + 2) * 64 + xt] = xf[k].z;
            xb[(d0 + 3) * 64 + xt] = xf[k].w;
        }
    };

    float acc[8][8];
#pragma unroll
    for (int i = 0; i < 8; ++i)
#pragma unroll
        for (int j = 0; j < 8; ++j) acc[i][j] = 0.0f;

    float4 xf[4];
    stageW(0, 0); loadX(xf, 0); writeX(xf, 0);
    __syncthreads();

    for (int c = 0; c < NC; ++c) {
        const int cur = c & 1;
        if (c + 1 < NC) { stageW(cur ^ 1, c + 1); loadX(xf, c + 1); }

        // compute wave's 16-d slice of chunk: 8x8 register tile, 4 LDS reads/d
        {
            const float* wb = lds + cur * BUFF + (wv * 16) * 64;   // W[d][e]
            const float* xb = wb + XOFF;                           // xT[d][t]
#pragma unroll 4
            for (int dd = 0; dd < 16; ++dd) {
                const float4 xa = *(const float4*)(xb + dd * 64 + tg * 8);
                const float4 xc = *(const float4*)(xb + dd * 64 + tg * 8 + 4);
                const float4 wa = *(const float4*)(wb + dd * 64 + eg * 8);
                const float4 wc = *(const float4*)(wb + dd * 64 + eg * 8 + 4);
                FMA_ROW(0, xa.x)
                FMA_ROW(1, xa.y)
                FMA_ROW(2, xa.z)
                FMA_ROW(3, xa.w)
                FMA_ROW(4, xc.x)
                FMA_ROW(5, xc.y)
                FMA_ROW(6, xc.z)
                FMA_ROW(7, xc.w)
            }
        }

        if (c + 1 < NC) writeX(xf, cur ^ 1);   // vmcnt-waits on xf, hidden by compute
        __syncthreads();
    }

    // ---- cross-wave k-reduction via LDS tiles (buffers are dead now)
    {
        float* tw = lds + wv * 4096;     // tile[wv][t][e]
#pragma unroll
        for (int i = 0; i < 8; ++i) {
            float4 lo = {acc[i][0], acc[i][1], acc[i][2], acc[i][3]};
            float4 hi = {acc[i][4], acc[i][5], acc[i][6], acc[i][7]};
            *(float4*)(tw + (tg * 8 + i) * 64 + eg * 8)     = lo;
            *(float4*)(tw + (tg * 8 + i) * 64 + eg * 8 + 4) = hi;
        }
    }
    __syncthreads();

    // ---- epilogue: wave wv owns tokens [wv*16, wv*16+16), lane = expert
    const float bias = b[lane];
    for (int tt = 0; tt < 16; ++tt) {
        const int t = wv * 16 + tt;
        float v = bias;
        v += lds[0 * 4096 + t * 64 + lane];
        v += lds[1 * 4096 + t * 64 + lane];
        v += lds[2 * 4096 + t * 64 + lane];
        v += lds[3 * 4096 + t * 64 + lane];

        // wave argmax, FIRST index on ties (matches jnp.argmax)
        float m = v; int mi = lane;
#pragma unroll
        for (int off = 32; off > 0; off >>= 1) {
            float om = __shfl_xor(m, off);
            int   oi = __shfl_xor(mi, off);
            if (om > m || (om == m && oi < mi)) { m = om; mi = oi; }
        }
        float s = __expf(v - m);
#pragma unroll
        for (int off = 32; off > 0; off >>= 1) s += __shfl_xor(s, off);
        const float g = 1.0f / s;   // top-1 gate = exp(0)/sum

        out[(size_t)(tok0 + t) * NEXP + lane] = (lane == mi) ? g : 0.0f;
        if (lane == mi) atomicAdd(&lds[DLDS + lane], g);
    }

    __syncthreads();
    if (tid < NEXP) atomicAdd(&denom[tid], lds[DLDS + tid]);
}

// out[n,e] *= capacity / (denom[e] + eps); zeros stay zero (branch-free)
__global__ __launch_bounds__(256)
void scale_kernel(float* __restrict__ out, const float* __restrict__ denom)
{
    __shared__ float sc[NEXP];
    if (threadIdx.x < NEXP)
        sc[threadIdx.x] = (float)NTOK / (denom[threadIdx.x] + 1e-6f);
    __syncthreads();

    const size_t i = (size_t)blockIdx.x * blockDim.x + threadIdx.x; // float4 idx
    float4 v = ((const float4*)out)[i];
    const int e0 = (int)((i * 4) & (NEXP - 1));
    v.x *= sc[e0]; v.y *= sc[e0 + 1]; v.z *= sc[e0 + 2]; v.w *= sc[e0 + 3];
    ((float4*)out)[i] = v;
}

extern "C" void kernel_launch(void* const* d_in, const int* in_sizes, int n_in,
                              void* d_out, int out_size, void* d_ws, size_t ws_size,
                              hipStream_t stream) {
    const float* x = (const float*)d_in[0];
    const float* w = (const float*)d_in[1];
    const float* b = (const float*)d_in[2];
    float* out   = (float*)d_out;
    float* denom = (float*)d_ws;   // 64 floats

    zero_denom_kernel<<<1, NEXP, 0, stream>>>(denom);
    gate_kernel<<<NBLK, 256, 0, stream>>>(x, w, b, out, denom);
    scale_kernel<<<(NTOK * NEXP / 4) / 256, 256, 0, stream>>>(out, denom);
}